// Round 1
// baseline (191.151 us; speedup 1.0000x reference)
//
#include <hip/hip_runtime.h>
#include <math.h>

#define B_  4
#define H_  496
#define W_  496
#define HW_ (H_ * W_)
#define N_  (B_ * HW_)

__global__ void iou_init(float* __restrict__ acc) {
    acc[0] = 0.f;
    acc[1] = 0.f;
}

__global__ __launch_bounds__(256) void iou_main(
    const float* __restrict__ iou_pred,
    const int*   __restrict__ mask,
    const float* __restrict__ box_pred,   // [B,7,H,W]
    const float* __restrict__ box_gt,     // [B,H,W,7]
    float* __restrict__ acc)              // acc[0]=sum(m*|d|), acc[1]=sum(m)
{
    // Per-thread polygon compaction buffer. Layout [vert][tid] as float2:
    // addr = vert*2048 + tid*8 -> 64 lanes x 2 dwords cover all 32 banks
    // exactly 4x per b64 access (minimum) -> conflict-free. Each thread only
    // touches its own column: NO __syncthreads needed around clip passes.
    __shared__ float2 lds[8][256];
    __shared__ float rn[4], rd[4];

    const int tid = threadIdx.x;
    const int n = blockIdx.x * 256 + tid;

    float num = 0.f, den = 0.f;
    if (n < N_) {
        const int b  = n / HW_;
        const int hw = n - b * HW_;

        // pred box: channel-strided [B,7,H,W]
        const float* bp = box_pred + (size_t)b * 7 * HW_ + hw;
        const float pax = bp[0];
        const float pay = bp[1 * HW_];
        const float paz = bp[2 * HW_];
        const float pdx = bp[3 * HW_];
        const float pdy = bp[4 * HW_];
        const float pdz = bp[5 * HW_];
        const float pr  = bp[6 * HW_];

        // gt box: contiguous [N,7]
        const float* bg = box_gt + (size_t)n * 7;
        const float gax = bg[0], gay = bg[1], gaz = bg[2];
        const float gdx = bg[3], gdy = bg[4], gdz = bg[5], gr = bg[6];

        float sp, cp; sincosf(pr, &sp, &cp);
        float sg, cg; sincosf(gr, &sg, &cg);
        const float phx = 0.5f * pdx, phy = 0.5f * pdy;
        const float ghx = 0.5f * gdx, ghy = 0.5f * gdy;

        // CCW corners, matching reference lx=[+,-,-,+]*hx, ly=[+,+,-,-]*hy
        float px[8], py[8];
        px[0] = pax + cp * phx - sp * phy;  py[0] = pay + sp * phx + cp * phy;
        px[1] = pax - cp * phx - sp * phy;  py[1] = pay - sp * phx + cp * phy;
        px[2] = pax - cp * phx + sp * phy;  py[2] = pay - sp * phx - cp * phy;
        px[3] = pax + cp * phx + sp * phy;  py[3] = pay + sp * phx - cp * phy;
#pragma unroll
        for (int k = 4; k < 8; ++k) { px[k] = 0.f; py[k] = 0.f; }

        float qx[4], qy[4];
        qx[0] = gax + cg * ghx - sg * ghy;  qy[0] = gay + sg * ghx + cg * ghy;
        qx[1] = gax - cg * ghx - sg * ghy;  qy[1] = gay - sg * ghx + cg * ghy;
        qx[2] = gax - cg * ghx + sg * ghy;  qy[2] = gay - sg * ghx - cg * ghy;
        qx[3] = gax + cg * ghx + sg * ghy;  qy[3] = gay + sg * ghx - cg * ghy;

        // Sutherland-Hodgman: clip pred-quad by each gt edge's left halfplane.
        int cnt = 4;
#pragma unroll
        for (int e = 0; e < 4; ++e) {
            const float ax = qx[e],        ay = qy[e];
            const float bx = qx[(e + 1) & 3], by = qy[(e + 1) & 3];
            const float ex = bx - ax, ey = by - ay;

            float d[8];
#pragma unroll
            for (int k = 0; k < 8; ++k)
                d[k] = ex * (py[k] - ay) - ey * (px[k] - ax);

            int oc = 0;
#pragma unroll
            for (int k = 0; k < 8; ++k) {
                const bool valid = (k < cnt);
                const bool wrap  = (k + 1 >= cnt);       // matches reference nidx rule
                const int  ks    = (k < 7) ? (k + 1) : 0; // compile-time index
                const float cx = px[k], cy = py[k], dc = d[k];
                const float nx = wrap ? px[0] : px[ks];
                const float ny = wrap ? py[0] : py[ks];
                const float dn = wrap ? d[0]  : d[ks];
                const bool inc = (dc >= 0.f);
                const bool inn = (dn >= 0.f);
                const bool keep = inc && valid;
                const bool crs  = (inc != inn) && valid;
                if (keep) {
                    if (oc < 8) lds[oc][tid] = make_float2(cx, cy);
                    ++oc;
                }
                if (crs) {
                    const float dd = dc - dn;
                    const float t  = dc / ((fabsf(dd) < 1e-9f) ? 1.f : dd);
                    if (oc < 8) lds[oc][tid] = make_float2(cx + t * (nx - cx),
                                                           cy + t * (ny - cy));
                    ++oc;
                }
            }
            cnt = oc;
#pragma unroll
            for (int k = 0; k < 8; ++k) {   // read back compacted polygon
                const float2 v = lds[k][tid];
                px[k] = v.x; py[k] = v.y;
            }
        }

        // shoelace over valid verts
        float s2 = 0.f;
#pragma unroll
        for (int k = 0; k < 8; ++k) {
            const bool valid = (k < cnt);
            const bool wrap  = (k + 1 >= cnt);
            const int  ks    = (k < 7) ? (k + 1) : 0;
            const float nx = wrap ? px[0] : px[ks];
            const float ny = wrap ? py[0] : py[ks];
            const float cr = px[k] * ny - nx * py[k];
            s2 += valid ? cr : 0.f;
        }
        const float inter_bev = 0.5f * fabsf(s2);

        const float za0 = paz - 0.5f * pdz, za1 = paz + 0.5f * pdz;
        const float zb0 = gaz - 0.5f * gdz, zb1 = gaz + 0.5f * gdz;
        const float zo  = fmaxf(fminf(za1, zb1) - fmaxf(za0, zb0), 0.f);
        const float iv  = inter_bev * zo;
        const float va  = pdx * pdy * pdz;
        const float vb  = gdx * gdy * gdz;
        const float iou = iv / (va + vb - iv + 1e-7f);
        const float target = 2.f * iou - 1.f;

        const float m = (float)mask[n];
        num = m * fabsf(iou_pred[n] - target);
        den = m;
    }

    // wave(64) shuffle reduction
#pragma unroll
    for (int off = 32; off > 0; off >>= 1) {
        num += __shfl_down(num, off);
        den += __shfl_down(den, off);
    }
    if ((tid & 63) == 0) { rn[tid >> 6] = num; rd[tid >> 6] = den; }
    __syncthreads();
    if (tid == 0) {
        atomicAdd(&acc[0], rn[0] + rn[1] + rn[2] + rn[3]);
        atomicAdd(&acc[1], rd[0] + rd[1] + rd[2] + rd[3]);
    }
}

__global__ void iou_fin(const float* __restrict__ acc, float* __restrict__ out) {
    out[0] = acc[0] / (acc[1] + 1e-4f);
}

extern "C" void kernel_launch(void* const* d_in, const int* in_sizes, int n_in,
                              void* d_out, int out_size, void* d_ws, size_t ws_size,
                              hipStream_t stream) {
    const float* iou_pred = (const float*)d_in[0];
    const int*   mask     = (const int*)  d_in[1];
    // d_in[2] = ind (unused by the layer)
    const float* box_pred = (const float*)d_in[3];
    const float* box_gt   = (const float*)d_in[4];
    float* out = (float*)d_out;
    float* acc = (float*)d_ws;   // 2 floats, re-poisoned each call -> init kernel

    iou_init<<<1, 1, 0, stream>>>(acc);
    iou_main<<<(N_ + 255) / 256, 256, 0, stream>>>(iou_pred, mask, box_pred, box_gt, acc);
    iou_fin<<<1, 1, 0, stream>>>(acc, out);
}

// Round 2
// 121.781 us; speedup vs baseline: 1.5696x; 1.5696x over previous
//
#include <hip/hip_runtime.h>
#include <math.h>

#define B_   4
#define H_   496
#define W_   496
#define HW_  (H_ * W_)
#define N_   (B_ * HW_)
#define NBLK (N_ / 256)          // 3844 exactly, no tail

static_assert(N_ % 256 == 0, "no tail");

// Sum over edges of P of cross(p0,p1) where [p0,p1] is the sub-segment of the
// edge inside convex CCW quad Q (Liang-Barsky, branch-free). Area(P∩Q) =
// 0.5*(clip_sum(P,Q) + clip_sum(Q,P)) since the intersection boundary is
// exactly {parts of ∂P in Q} ∪ {parts of ∂Q in P} and the line integral
// x dy - y dx is additive over pieces in any order.
__device__ __forceinline__ float clip_sum(const float px[4], const float py[4],
                                          const float qx[4], const float qy[4]) {
    float ex[4], ey[4];
#pragma unroll
    for (int i = 0; i < 4; ++i) {
        ex[i] = qx[(i + 1) & 3] - qx[i];
        ey[i] = qy[(i + 1) & 3] - qy[i];
    }
    // F[i][k] = signed dist of P vertex k against Q edge i (>=0 == inside, CCW)
    float F[4][4];
#pragma unroll
    for (int i = 0; i < 4; ++i)
#pragma unroll
        for (int k = 0; k < 4; ++k)
            F[i][k] = ex[i] * (py[k] - qy[i]) - ey[i] * (px[k] - qx[i]);

    float s = 0.f;
#pragma unroll
    for (int k = 0; k < 4; ++k) {
        const int   k1 = (k + 1) & 3;
        const float ax = px[k], ay = py[k];
        const float dx = px[k1] - ax, dy = py[k1] - ay;
        float t0 = 0.f, t1 = 1.f;
#pragma unroll
        for (int i = 0; i < 4; ++i) {
            const float fa = F[i][k], fb = F[i][k1];
            const float df = fb - fa;
            const float dfs = (df == 0.f) ? 1e-30f : df;
            const float tc = __fdividef(-fa, dfs);
            t0 = fmaxf(t0, (df > 0.f) ? tc : 0.f);   // entering constraint
            t1 = fminf(t1, (df < 0.f) ? tc : 1.f);   // exiting constraint
            if (df == 0.f && fa < 0.f) t0 = 2.f;     // parallel & outside
        }
        const float x0 = ax + t0 * dx, y0 = ay + t0 * dy;
        const float x1 = ax + t1 * dx, y1 = ay + t1 * dy;
        const float c  = x0 * y1 - x1 * y0;
        s += (t1 > t0) ? c : 0.f;
    }
    return s;
}

__global__ __launch_bounds__(256) void iou_main(
    const float* __restrict__ iou_pred,
    const int*   __restrict__ mask,
    const float* __restrict__ box_pred,   // [B,7,H,W]
    const float* __restrict__ box_gt,     // [B,H,W,7]
    float* __restrict__ ws)               // ws[0..NBLK)=num, ws[NBLK..2N)=den
{
    __shared__ float rn[4], rd[4];
    const int tid = threadIdx.x;
    const int n = blockIdx.x * 256 + tid;

    const int b  = n / HW_;
    const int hw = n - b * HW_;

    const float* bp = box_pred + (size_t)b * 7 * HW_ + hw;
    const float pax = bp[0];
    const float pay = bp[1 * HW_];
    const float paz = bp[2 * HW_];
    const float pdx = bp[3 * HW_];
    const float pdy = bp[4 * HW_];
    const float pdz = bp[5 * HW_];
    const float pr  = bp[6 * HW_];

    const float* bg = box_gt + (size_t)n * 7;
    const float gax = bg[0], gay = bg[1], gaz = bg[2];
    const float gdx = bg[3], gdy = bg[4], gdz = bg[5], gr = bg[6];

    float sp, cp; __sincosf(pr, &sp, &cp);
    float sg, cg; __sincosf(gr, &sg, &cg);
    const float phx = 0.5f * pdx, phy = 0.5f * pdy;
    const float ghx = 0.5f * gdx, ghy = 0.5f * gdy;

    // CCW corners (matches reference lx=[+,-,-,+]*hx, ly=[+,+,-,-]*hy)
    float px[4], py[4], qx[4], qy[4];
    px[0] = pax + cp * phx - sp * phy;  py[0] = pay + sp * phx + cp * phy;
    px[1] = pax - cp * phx - sp * phy;  py[1] = pay - sp * phx + cp * phy;
    px[2] = pax - cp * phx + sp * phy;  py[2] = pay - sp * phx - cp * phy;
    px[3] = pax + cp * phx + sp * phy;  py[3] = pay + sp * phx - cp * phy;
    qx[0] = gax + cg * ghx - sg * ghy;  qy[0] = gay + sg * ghx + cg * ghy;
    qx[1] = gax - cg * ghx - sg * ghy;  qy[1] = gay - sg * ghx + cg * ghy;
    qx[2] = gax - cg * ghx + sg * ghy;  qy[2] = gay - sg * ghx - cg * ghy;
    qx[3] = gax + cg * ghx + sg * ghy;  qy[3] = gay + sg * ghx - cg * ghy;

    const float inter_bev = 0.5f * (clip_sum(px, py, qx, qy) +
                                    clip_sum(qx, qy, px, py));

    const float za0 = paz - 0.5f * pdz, za1 = paz + 0.5f * pdz;
    const float zb0 = gaz - 0.5f * gdz, zb1 = gaz + 0.5f * gdz;
    const float zo  = fmaxf(fminf(za1, zb1) - fmaxf(za0, zb0), 0.f);
    const float iv  = inter_bev * zo;
    const float va  = pdx * pdy * pdz;
    const float vb  = gdx * gdy * gdz;
    const float iou = iv / (va + vb - iv + 1e-7f);
    const float target = 2.f * iou - 1.f;

    const float m = (float)mask[n];
    float num = m * fabsf(iou_pred[n] - target);
    float den = m;

#pragma unroll
    for (int off = 32; off > 0; off >>= 1) {
        num += __shfl_down(num, off);
        den += __shfl_down(den, off);
    }
    if ((tid & 63) == 0) { rn[tid >> 6] = num; rd[tid >> 6] = den; }
    __syncthreads();
    if (tid == 0) {
        ws[blockIdx.x]        = rn[0] + rn[1] + rn[2] + rn[3];
        ws[NBLK + blockIdx.x] = rd[0] + rd[1] + rd[2] + rd[3];
    }
}

__global__ __launch_bounds__(256) void iou_fin(const float* __restrict__ ws,
                                               float* __restrict__ out) {
    __shared__ float rn[4], rd[4];
    float sn = 0.f, sd = 0.f;
    for (int i = threadIdx.x; i < NBLK; i += 256) {
        sn += ws[i];
        sd += ws[NBLK + i];
    }
#pragma unroll
    for (int off = 32; off > 0; off >>= 1) {
        sn += __shfl_down(sn, off);
        sd += __shfl_down(sd, off);
    }
    const int tid = threadIdx.x;
    if ((tid & 63) == 0) { rn[tid >> 6] = sn; rd[tid >> 6] = sd; }
    __syncthreads();
    if (tid == 0)
        out[0] = (rn[0] + rn[1] + rn[2] + rn[3]) /
                 (rd[0] + rd[1] + rd[2] + rd[3] + 1e-4f);
}

extern "C" void kernel_launch(void* const* d_in, const int* in_sizes, int n_in,
                              void* d_out, int out_size, void* d_ws, size_t ws_size,
                              hipStream_t stream) {
    const float* iou_pred = (const float*)d_in[0];
    const int*   mask     = (const int*)  d_in[1];
    // d_in[2] = ind (unused by the layer)
    const float* box_pred = (const float*)d_in[3];
    const float* box_gt   = (const float*)d_in[4];
    float* out = (float*)d_out;
    float* ws  = (float*)d_ws;   // 2*NBLK floats of plain partials (no init needed)

    iou_main<<<NBLK, 256, 0, stream>>>(iou_pred, mask, box_pred, box_gt, ws);
    iou_fin<<<1, 256, 0, stream>>>(ws, out);
}